// Round 1
// baseline (2900.272 us; speedup 1.0000x reference)
//
#include <hip/hip_runtime.h>

#define BATCH 4
#define NPTS  4096
#define NC    1024
#define KNN   32
#define CIN   128
#define CO    256

// output layout (flat f32, reference return order)
#define OFF_CXYZ 0
#define OFF_CMAD (BATCH*NC*3)                 // 12288
#define OFF_CADJ (OFF_CMAD + BATCH*NC*3)     // 24576
#define OFF_CPT  (OFF_CADJ + BATCH*NC*2)     // 32768
#define OFF_OMAD (OFF_CPT  + BATCH*NC*4)     // 49152
#define OFF_OADJ (OFF_OMAD + BATCH*NC*CO)
#define OFF_OPT  (OFF_OADJ + BATCH*NC*CO)
#define OFF_OCST (OFF_OPT  + BATCH*NC*CO)

// ---------------------------------------------------------------------------
// FPS: one block per batch, 1024 threads x 4 points each. Sequential 1024
// steps; exact np f32 op order via _rn intrinsics; argmax lowest-index ties.
// ---------------------------------------------------------------------------
__global__ __launch_bounds__(1024) void fps_kernel(const float* __restrict__ xyz,
                                                   int* __restrict__ fps_idx)
{
    const int b = blockIdx.x;
    const int t = threadIdx.x;
    const float* xb = xyz + (size_t)b * NPTS * 3;
    float px[4], py[4], pz[4], dd[4];
#pragma unroll
    for (int i = 0; i < 4; ++i) {
        int p = t + i * 1024;
        px[i] = xb[p*3+0]; py[i] = xb[p*3+1]; pz[i] = xb[p*3+2];
        dd[i] = 1e10f;
    }
    __shared__ float s_val[16];
    __shared__ int   s_idx[16];
    __shared__ int   s_far;
    int far = 0;
    for (int s = 0; s < NC; ++s) {
        if (t == 0) fps_idx[b*NC + s] = far;
        const float cx = xb[far*3+0], cy = xb[far*3+1], cz = xb[far*3+2];
        float bv = -1.0f; int bi = 0;
#pragma unroll
        for (int i = 0; i < 4; ++i) {
            float dx = __fsub_rn(px[i], cx);
            float dy = __fsub_rn(py[i], cy);
            float dz = __fsub_rn(pz[i], cz);
            float d  = __fadd_rn(__fadd_rn(__fmul_rn(dx,dx), __fmul_rn(dy,dy)), __fmul_rn(dz,dz));
            float nd = fminf(dd[i], d);
            dd[i] = nd;
            if (nd > bv) { bv = nd; bi = t + i*1024; }   // i ascending => lowest idx kept on tie
        }
#pragma unroll
        for (int off = 32; off; off >>= 1) {
            float ov = __shfl_xor(bv, off);
            int   oi = __shfl_xor(bi, off);
            if (ov > bv || (ov == bv && oi < bi)) { bv = ov; bi = oi; }
        }
        if ((t & 63) == 0) { s_val[t>>6] = bv; s_idx[t>>6] = bi; }
        __syncthreads();
        if (t == 0) {
            float v = s_val[0]; int w = s_idx[0];
#pragma unroll
            for (int r = 1; r < 16; ++r)
                if (s_val[r] > v || (s_val[r] == v && s_idx[r] < w)) { v = s_val[r]; w = s_idx[r]; }
            s_far = w;
        }
        __syncthreads();
        far = s_far;
    }
}

// ---------------------------------------------------------------------------
// kNN for the selected centers only. One block per (b,s). Distances via the
// reference formula sq_c + sq_m - 2*dot (np op order), 32 sequential argmins
// with lowest-index tie-break (matches lax.top_k set semantics).
// ---------------------------------------------------------------------------
__global__ __launch_bounds__(256) void knn_kernel(const float* __restrict__ xyz,
                                                  const int* __restrict__ fps_idx,
                                                  int* __restrict__ nbr_idx)
{
    const int bs = blockIdx.x;
    const int b  = bs >> 10;
    const int t  = threadIdx.x;
    const float* xb = xyz + (size_t)b * NPTS * 3;
    const int ci = fps_idx[bs];
    const float cx = xb[ci*3], cy = xb[ci*3+1], cz = xb[ci*3+2];
    const float sqc = __fadd_rn(__fadd_rn(__fmul_rn(cx,cx), __fmul_rn(cy,cy)), __fmul_rn(cz,cz));
    __shared__ float dist[NPTS];
    for (int i = t; i < NPTS; i += 256) {
        float x = xb[i*3], y = xb[i*3+1], z = xb[i*3+2];
        float sqm = __fadd_rn(__fadd_rn(__fmul_rn(x,x), __fmul_rn(y,y)), __fmul_rn(z,z));
        float dot = __fadd_rn(__fadd_rn(__fmul_rn(cx,x), __fmul_rn(cy,y)), __fmul_rn(cz,z));
        dist[i] = __fsub_rn(__fadd_rn(sqc, sqm), __fmul_rn(2.0f, dot));
    }
    __syncthreads();
    __shared__ float s_val[4];
    __shared__ int   s_idx[4];
    for (int kk = 0; kk < KNN; ++kk) {
        float bv = 3.0e38f; int bi = 0x7fffffff;
        for (int i = t; i < NPTS; i += 256) {
            float v = dist[i];
            if (v < bv) { bv = v; bi = i; }   // i ascending => lowest idx on tie
        }
#pragma unroll
        for (int off = 32; off; off >>= 1) {
            float ov = __shfl_xor(bv, off);
            int   oi = __shfl_xor(bi, off);
            if (ov < bv || (ov == bv && oi < bi)) { bv = ov; bi = oi; }
        }
        if ((t & 63) == 0) { s_val[t>>6] = bv; s_idx[t>>6] = bi; }
        __syncthreads();
        if (t == 0) {
            float v = s_val[0]; int w = s_idx[0];
#pragma unroll
            for (int r = 1; r < 4; ++r)
                if (s_val[r] < v || (s_val[r] == v && s_idx[r] < w)) { v = s_val[r]; w = s_idx[r]; }
            nbr_idx[bs*KNN + kk] = w;
            dist[w] = 3.0e38f;
        }
        __syncthreads();
    }
}

// ---------------------------------------------------------------------------
// Factorized attention: scores = (Wk·q)·fea, o = Wv^T·(sum_k attn_k fea_k).
// One block per (b,s), 256 threads. TYPE: 0=mad 1=adj 2=pt 3=cst.
// ---------------------------------------------------------------------------
template<int TYPE>
__device__ __forceinline__ void attn_type(
    int b, int bs, int ci,
    const float* __restrict__ fea, const float* __restrict__ aux,
    const float* __restrict__ Wq, const float* __restrict__ Wk, const float* __restrict__ Wv,
    float* __restrict__ outp,
    float* s_cf, float* s_q, float* s_u, float (*s_fea)[136],
    float* s_sc, float* s_caux, float* s_wf, const int* s_nbr)
{
    constexpr int D    = (TYPE==2) ? 136 : (TYPE==1) ? 132 : 131;
    constexpr int AUXC = (TYPE==2) ? 4   : (TYPE==1) ? 2   : 3;
    const int t = threadIdx.x;
    const int g = t >> 5, l = t & 31;

    // center feature + center aux
    if (t < CIN) s_cf[t] = fea[(size_t)(b*NPTS + ci)*CIN + t];
    if (t >= CIN && t < CIN + AUXC) s_caux[t-CIN] = aux[(size_t)(b*NPTS + ci)*AUXC + (t-CIN)];
    __syncthreads();

    // q_h = sum_c cf[c] * Wq[c,h]
    float q = 0.f;
#pragma unroll 16
    for (int c = 0; c < CIN; ++c) q = fmaf(s_cf[c], Wq[c*CO + t], q);
    s_q[t] = q;
    __syncthreads();

    // u_d = sum_h Wk[d,h] * q[h]   (8 half-wave groups, coalesced Wk rows)
    for (int d0 = 0; d0 < D; d0 += 8) {
        int d = d0 + g;
        float acc = 0.f;
        if (d < D) {
            const float* wrow = Wk + (size_t)d * CO;
#pragma unroll
            for (int h = l; h < CO; h += 32) acc = fmaf(wrow[h], s_q[h], acc);
        }
#pragma unroll
        for (int off = 16; off; off >>= 1) acc += __shfl_xor(acc, off);
        if (l == 0 && d < D) s_u[d] = acc;
    }

    // gather all 32 neighbor features (+ aux concat) into LDS
    for (int i = t; i < KNN*CIN; i += 256) {
        int kk = i >> 7, c = i & 127;
        s_fea[kk][c] = fea[(size_t)(b*NPTS + s_nbr[kk])*CIN + c];
    }
    if (t < KNN) {
        int j = s_nbr[t];
        if (TYPE == 0 || TYPE == 3) {
#pragma unroll
            for (int i2 = 0; i2 < 3; ++i2)
                s_fea[t][CIN+i2] = aux[(size_t)(b*NPTS + j)*3 + i2] - s_caux[i2];
        } else if (TYPE == 1) {
            s_fea[t][CIN+0] = aux[(size_t)(b*NPTS + j)*2 + 0];
            s_fea[t][CIN+1] = aux[(size_t)(b*NPTS + j)*2 + 1];
            s_fea[t][CIN+2] = s_caux[0];
            s_fea[t][CIN+3] = s_caux[1];
        } else {
#pragma unroll
            for (int i2 = 0; i2 < 4; ++i2) s_fea[t][CIN+i2]   = aux[(size_t)(b*NPTS + j)*4 + i2];
#pragma unroll
            for (int i2 = 0; i2 < 4; ++i2) s_fea[t][CIN+4+i2] = s_caux[i2];
        }
    }
    __syncthreads();

    // scores_k = (u . fea_k) / 16
#pragma unroll
    for (int it = 0; it < 4; ++it) {
        int kk = it*8 + g;
        float acc = 0.f;
        for (int d = l; d < D; d += 32) acc = fmaf(s_fea[kk][d], s_u[d], acc);
#pragma unroll
        for (int off = 16; off; off >>= 1) acc += __shfl_xor(acc, off);
        if (l == 0) s_sc[kk] = acc * 0.0625f;
    }
    __syncthreads();

    // softmax over 32 (lanes 0..31 of wave 0)
    if (t < KNN) {
        float sc = s_sc[t];
        float m = sc;
#pragma unroll
        for (int off = 16; off; off >>= 1) m = fmaxf(m, __shfl_xor(m, off));
        float e = expf(sc - m);
        float ssum = e;
#pragma unroll
        for (int off = 16; off; off >>= 1) ssum += __shfl_xor(ssum, off);
        s_sc[t] = e / ssum;
    }
    __syncthreads();

    // wfea_d = sum_k attn_k * fea_k[d]
    if (t < D) {
        float wf = 0.f;
#pragma unroll
        for (int kk = 0; kk < KNN; ++kk) wf = fmaf(s_sc[kk], s_fea[kk][t], wf);
        s_wf[t] = wf;
    }
    __syncthreads();

    // o_h = sum_d wfea_d * Wv[d,h]
    float o = 0.f;
#pragma unroll 8
    for (int d = 0; d < D; ++d) o = fmaf(s_wf[d], Wv[(size_t)d*CO + t], o);
    outp[(size_t)bs*CO + t] = o;
    __syncthreads();
}

__global__ __launch_bounds__(256) void attn_kernel(
    const float* __restrict__ xyz, const float* __restrict__ mad,
    const float* __restrict__ adj, const float* __restrict__ pt,
    const float* __restrict__ mad_fea, const float* __restrict__ adj_fea,
    const float* __restrict__ pt_fea,  const float* __restrict__ cst_fea,
    const float* __restrict__ wq_mad, const float* __restrict__ wk_mad, const float* __restrict__ wv_mad,
    const float* __restrict__ wq_adj, const float* __restrict__ wk_adj, const float* __restrict__ wv_adj,
    const float* __restrict__ wq_pt,  const float* __restrict__ wk_pt,  const float* __restrict__ wv_pt,
    const float* __restrict__ wq_cst, const float* __restrict__ wk_cst, const float* __restrict__ wv_cst,
    const int* __restrict__ fps_idx, const int* __restrict__ nbr_idx,
    float* __restrict__ out)
{
    __shared__ float s_cf[CIN];
    __shared__ float s_q[CO];
    __shared__ float s_u[136];
    __shared__ float s_fea[KNN][136];
    __shared__ float s_sc[KNN];
    __shared__ float s_caux[4];
    __shared__ float s_wf[136];
    __shared__ int   s_nbr[KNN];

    const int bs = blockIdx.x;
    const int b  = bs >> 10;
    const int t  = threadIdx.x;
    const int ci = fps_idx[bs];

    if (t < KNN) s_nbr[t] = nbr_idx[bs*KNN + t];
    // center gathers (small outputs)
    if (t < 3)                 out[OFF_CXYZ + bs*3 + t]      = xyz[(size_t)(b*NPTS+ci)*3 + t];
    if (t >= 64 && t < 67)     out[OFF_CMAD + bs*3 + (t-64)] = mad[(size_t)(b*NPTS+ci)*3 + (t-64)];
    if (t >= 96 && t < 98)     out[OFF_CADJ + bs*2 + (t-96)] = adj[(size_t)(b*NPTS+ci)*2 + (t-96)];
    if (t >= 128 && t < 132)   out[OFF_CPT  + bs*4 + (t-128)] = pt[(size_t)(b*NPTS+ci)*4 + (t-128)];
    __syncthreads();

    attn_type<0>(b, bs, ci, mad_fea, mad, wq_mad, wk_mad, wv_mad, out + OFF_OMAD,
                 s_cf, s_q, s_u, s_fea, s_sc, s_caux, s_wf, s_nbr);
    attn_type<1>(b, bs, ci, adj_fea, adj, wq_adj, wk_adj, wv_adj, out + OFF_OADJ,
                 s_cf, s_q, s_u, s_fea, s_sc, s_caux, s_wf, s_nbr);
    attn_type<2>(b, bs, ci, pt_fea,  pt,  wq_pt,  wk_pt,  wv_pt,  out + OFF_OPT,
                 s_cf, s_q, s_u, s_fea, s_sc, s_caux, s_wf, s_nbr);
    attn_type<3>(b, bs, ci, cst_fea, xyz, wq_cst, wk_cst, wv_cst, out + OFF_OCST,
                 s_cf, s_q, s_u, s_fea, s_sc, s_caux, s_wf, s_nbr);
}

extern "C" void kernel_launch(void* const* d_in, const int* in_sizes, int n_in,
                              void* d_out, int out_size, void* d_ws, size_t ws_size,
                              hipStream_t stream)
{
    const float* xyz     = (const float*)d_in[0];
    const float* mad     = (const float*)d_in[1];
    const float* adj     = (const float*)d_in[2];
    const float* pt      = (const float*)d_in[3];
    const float* mad_fea = (const float*)d_in[4];
    const float* adj_fea = (const float*)d_in[5];
    const float* pt_fea  = (const float*)d_in[6];
    const float* cst_fea = (const float*)d_in[7];
    const float* wq_mad  = (const float*)d_in[8];
    const float* wk_mad  = (const float*)d_in[9];
    const float* wv_mad  = (const float*)d_in[10];
    const float* wq_adj  = (const float*)d_in[11];
    const float* wk_adj  = (const float*)d_in[12];
    const float* wv_adj  = (const float*)d_in[13];
    const float* wq_pt   = (const float*)d_in[14];
    const float* wk_pt   = (const float*)d_in[15];
    const float* wv_pt   = (const float*)d_in[16];
    const float* wq_cst  = (const float*)d_in[17];
    const float* wk_cst  = (const float*)d_in[18];
    const float* wv_cst  = (const float*)d_in[19];
    float* out = (float*)d_out;

    int* fps_idx = (int*)d_ws;                      // BATCH*NC ints
    int* nbr_idx = fps_idx + BATCH*NC;              // BATCH*NC*KNN ints

    fps_kernel<<<BATCH, 1024, 0, stream>>>(xyz, fps_idx);
    knn_kernel<<<BATCH*NC, 256, 0, stream>>>(xyz, fps_idx, nbr_idx);
    attn_kernel<<<BATCH*NC, 256, 0, stream>>>(xyz, mad, adj, pt,
        mad_fea, adj_fea, pt_fea, cst_fea,
        wq_mad, wk_mad, wv_mad, wq_adj, wk_adj, wv_adj,
        wq_pt, wk_pt, wv_pt, wq_cst, wk_cst, wv_cst,
        fps_idx, nbr_idx, out);
}

// Round 2
// 1781.788 us; speedup vs baseline: 1.6277x; 1.6277x over previous
//
#include <hip/hip_runtime.h>

#define BATCH 4
#define NPTS  4096
#define NC    1024
#define KNN   32
#define CIN   128
#define CO    256

// output layout (flat f32, reference return order)
#define OFF_CXYZ 0
#define OFF_CMAD (BATCH*NC*3)                 // 12288
#define OFF_CADJ (OFF_CMAD + BATCH*NC*3)     // 24576
#define OFF_CPT  (OFF_CADJ + BATCH*NC*2)     // 32768
#define OFF_OMAD (OFF_CPT  + BATCH*NC*4)     // 49152
#define OFF_OADJ (OFF_OMAD + BATCH*NC*CO)
#define OFF_OPT  (OFF_OADJ + BATCH*NC*CO)
#define OFF_OCST (OFF_OPT  + BATCH*NC*CO)

// ---------------------------------------------------------------------------
// FPS: one block per batch, 256 threads x 16 points in REGISTERS.
// One barrier per iteration: wave leaders post candidates to double-buffered
// LDS; all threads redundantly pick the winner (no 2nd barrier, no t0 scan).
// Center coords come from an LDS-staged float4 copy of xyz.
// Exact np f32 op order via _rn intrinsics; argmax lowest-index tie-break.
// ---------------------------------------------------------------------------
__global__ __launch_bounds__(256) void fps_kernel(const float* __restrict__ xyz,
                                                  int* __restrict__ fps_idx)
{
    const int b = blockIdx.x;
    const int t = threadIdx.x;
    const float* xb = xyz + (size_t)b * NPTS * 3;

    __shared__ float4 s_xyz[NPTS];          // 64 KB
    __shared__ float  s_val[2][4];
    __shared__ int    s_idx[2][4];

    float px[16], py[16], pz[16], dd[16];
#pragma unroll
    for (int i = 0; i < 16; ++i) {
        int p = t + i * 256;
        px[i] = xb[p*3+0]; py[i] = xb[p*3+1]; pz[i] = xb[p*3+2];
        s_xyz[p] = make_float4(px[i], py[i], pz[i], 0.f);
        dd[i] = 1e10f;
    }
    __syncthreads();

    int far = 0;
    for (int s = 0; s < NC; ++s) {
        if (t == 0) fps_idx[b*NC + s] = far;
        const float4 c = s_xyz[far];
        float bv = -1.0f; int bi = 0;
#pragma unroll
        for (int i = 0; i < 16; ++i) {
            float dx = __fsub_rn(px[i], c.x);
            float dy = __fsub_rn(py[i], c.y);
            float dz = __fsub_rn(pz[i], c.z);
            float d  = __fadd_rn(__fadd_rn(__fmul_rn(dx,dx), __fmul_rn(dy,dy)), __fmul_rn(dz,dz));
            float nd = fminf(dd[i], d);
            dd[i] = nd;
            if (nd > bv) { bv = nd; bi = t + i*256; }   // ascending p => lowest idx on tie
        }
#pragma unroll
        for (int off = 32; off; off >>= 1) {
            float ov = __shfl_xor(bv, off);
            int   oi = __shfl_xor(bi, off);
            if (ov > bv || (ov == bv && oi < bi)) { bv = ov; bi = oi; }
        }
        const int buf = s & 1;
        if ((t & 63) == 0) { s_val[buf][t>>6] = bv; s_idx[buf][t>>6] = bi; }
        __syncthreads();
        float v = s_val[buf][0]; int w = s_idx[buf][0];
#pragma unroll
        for (int r = 1; r < 4; ++r) {
            float rv = s_val[buf][r]; int ri = s_idx[buf][r];
            if (rv > v || (rv == v && ri < w)) { v = rv; w = ri; }
        }
        far = w;
    }
}

// ---------------------------------------------------------------------------
// kNN for the selected centers only. One block per (b,s), 256 threads,
// 16 distances per thread held in REGISTERS. 32 selection passes, one
// barrier each; removal = owning thread poisons its own register.
// Distances via the reference formula sq_c + sq_m - 2*dot (np op order);
// lowest-index tie-break (matches lax.top_k set semantics).
// ---------------------------------------------------------------------------
__global__ __launch_bounds__(256) void knn_kernel(const float* __restrict__ xyz,
                                                  const int* __restrict__ fps_idx,
                                                  int* __restrict__ nbr_idx)
{
    const int bs = blockIdx.x;
    const int b  = bs >> 10;
    const int t  = threadIdx.x;
    const float* xb = xyz + (size_t)b * NPTS * 3;
    const int ci = fps_idx[bs];
    const float cx = xb[ci*3], cy = xb[ci*3+1], cz = xb[ci*3+2];
    const float sqc = __fadd_rn(__fadd_rn(__fmul_rn(cx,cx), __fmul_rn(cy,cy)), __fmul_rn(cz,cz));

    float rd[16];
#pragma unroll
    for (int i = 0; i < 16; ++i) {
        int p = t + i * 256;
        float x = xb[p*3], y = xb[p*3+1], z = xb[p*3+2];
        float sqm = __fadd_rn(__fadd_rn(__fmul_rn(x,x), __fmul_rn(y,y)), __fmul_rn(z,z));
        float dot = __fadd_rn(__fadd_rn(__fmul_rn(cx,x), __fmul_rn(cy,y)), __fmul_rn(cz,z));
        rd[i] = __fsub_rn(__fadd_rn(sqc, sqm), __fmul_rn(2.0f, dot));
    }

    __shared__ float s_val[2][4];
    __shared__ int   s_idx[2][4];

    for (int kk = 0; kk < KNN; ++kk) {
        float bv = 3.0e38f; int bi = 0x7fffffff;
#pragma unroll
        for (int i = 0; i < 16; ++i) {
            float vv = rd[i];
            if (vv < bv) { bv = vv; bi = t + i*256; }   // ascending p => lowest idx on tie
        }
#pragma unroll
        for (int off = 32; off; off >>= 1) {
            float ov = __shfl_xor(bv, off);
            int   oi = __shfl_xor(bi, off);
            if (ov < bv || (ov == bv && oi < bi)) { bv = ov; bi = oi; }
        }
        const int buf = kk & 1;
        if ((t & 63) == 0) { s_val[buf][t>>6] = bv; s_idx[buf][t>>6] = bi; }
        __syncthreads();
        float v = s_val[buf][0]; int w = s_idx[buf][0];
#pragma unroll
        for (int r = 1; r < 4; ++r) {
            float rv = s_val[buf][r]; int ri = s_idx[buf][r];
            if (rv < v || (rv == v && ri < w)) { v = rv; w = ri; }
        }
        if (t == 0) nbr_idx[bs*KNN + kk] = w;
        if ((w & 255) == t) rd[w >> 8] = 3.0e38f;       // remove from my registers
    }
}

// ---------------------------------------------------------------------------
// Factorized attention: scores = (Wk·q)·fea, o = Wv^T·(sum_k attn_k fea_k).
// One block per (b,s), 256 threads. TYPE: 0=mad 1=adj 2=pt 3=cst.
// ---------------------------------------------------------------------------
template<int TYPE>
__device__ __forceinline__ void attn_type(
    int b, int bs, int ci,
    const float* __restrict__ fea, const float* __restrict__ aux,
    const float* __restrict__ Wq, const float* __restrict__ Wk, const float* __restrict__ Wv,
    float* __restrict__ outp,
    float* s_cf, float* s_q, float* s_u, float (*s_fea)[136],
    float* s_sc, float* s_caux, float* s_wf, const int* s_nbr)
{
    constexpr int D    = (TYPE==2) ? 136 : (TYPE==1) ? 132 : 131;
    constexpr int AUXC = (TYPE==2) ? 4   : (TYPE==1) ? 2   : 3;
    const int t = threadIdx.x;
    const int g = t >> 5, l = t & 31;

    // center feature + center aux
    if (t < CIN) s_cf[t] = fea[(size_t)(b*NPTS + ci)*CIN + t];
    if (t >= CIN && t < CIN + AUXC) s_caux[t-CIN] = aux[(size_t)(b*NPTS + ci)*AUXC + (t-CIN)];
    __syncthreads();

    // q_h = sum_c cf[c] * Wq[c,h]
    float q = 0.f;
#pragma unroll 16
    for (int c = 0; c < CIN; ++c) q = fmaf(s_cf[c], Wq[c*CO + t], q);
    s_q[t] = q;
    __syncthreads();

    // u_d = sum_h Wk[d,h] * q[h]   (8 half-wave groups, coalesced Wk rows)
    for (int d0 = 0; d0 < D; d0 += 8) {
        int d = d0 + g;
        float acc = 0.f;
        if (d < D) {
            const float* wrow = Wk + (size_t)d * CO;
#pragma unroll
            for (int h = l; h < CO; h += 32) acc = fmaf(wrow[h], s_q[h], acc);
        }
#pragma unroll
        for (int off = 16; off; off >>= 1) acc += __shfl_xor(acc, off);
        if (l == 0 && d < D) s_u[d] = acc;
    }

    // gather all 32 neighbor features (+ aux concat) into LDS
    for (int i = t; i < KNN*CIN; i += 256) {
        int kk = i >> 7, c = i & 127;
        s_fea[kk][c] = fea[(size_t)(b*NPTS + s_nbr[kk])*CIN + c];
    }
    if (t < KNN) {
        int j = s_nbr[t];
        if (TYPE == 0 || TYPE == 3) {
#pragma unroll
            for (int i2 = 0; i2 < 3; ++i2)
                s_fea[t][CIN+i2] = aux[(size_t)(b*NPTS + j)*3 + i2] - s_caux[i2];
        } else if (TYPE == 1) {
            s_fea[t][CIN+0] = aux[(size_t)(b*NPTS + j)*2 + 0];
            s_fea[t][CIN+1] = aux[(size_t)(b*NPTS + j)*2 + 1];
            s_fea[t][CIN+2] = s_caux[0];
            s_fea[t][CIN+3] = s_caux[1];
        } else {
#pragma unroll
            for (int i2 = 0; i2 < 4; ++i2) s_fea[t][CIN+i2]   = aux[(size_t)(b*NPTS + j)*4 + i2];
#pragma unroll
            for (int i2 = 0; i2 < 4; ++i2) s_fea[t][CIN+4+i2] = s_caux[i2];
        }
    }
    __syncthreads();

    // scores_k = (u . fea_k) / 16
#pragma unroll
    for (int it = 0; it < 4; ++it) {
        int kk = it*8 + g;
        float acc = 0.f;
        for (int d = l; d < D; d += 32) acc = fmaf(s_fea[kk][d], s_u[d], acc);
#pragma unroll
        for (int off = 16; off; off >>= 1) acc += __shfl_xor(acc, off);
        if (l == 0) s_sc[kk] = acc * 0.0625f;
    }
    __syncthreads();

    // softmax over 32 (lanes 0..31 of wave 0)
    if (t < KNN) {
        float sc = s_sc[t];
        float m = sc;
#pragma unroll
        for (int off = 16; off; off >>= 1) m = fmaxf(m, __shfl_xor(m, off));
        float e = expf(sc - m);
        float ssum = e;
#pragma unroll
        for (int off = 16; off; off >>= 1) ssum += __shfl_xor(ssum, off);
        s_sc[t] = e / ssum;
    }
    __syncthreads();

    // wfea_d = sum_k attn_k * fea_k[d]
    if (t < D) {
        float wf = 0.f;
#pragma unroll
        for (int kk = 0; kk < KNN; ++kk) wf = fmaf(s_sc[kk], s_fea[kk][t], wf);
        s_wf[t] = wf;
    }
    __syncthreads();

    // o_h = sum_d wfea_d * Wv[d,h]
    float o = 0.f;
#pragma unroll 8
    for (int d = 0; d < D; ++d) o = fmaf(s_wf[d], Wv[(size_t)d*CO + t], o);
    outp[(size_t)bs*CO + t] = o;
    __syncthreads();
}

__global__ __launch_bounds__(256) void attn_kernel(
    const float* __restrict__ xyz, const float* __restrict__ mad,
    const float* __restrict__ adj, const float* __restrict__ pt,
    const float* __restrict__ mad_fea, const float* __restrict__ adj_fea,
    const float* __restrict__ pt_fea,  const float* __restrict__ cst_fea,
    const float* __restrict__ wq_mad, const float* __restrict__ wk_mad, const float* __restrict__ wv_mad,
    const float* __restrict__ wq_adj, const float* __restrict__ wk_adj, const float* __restrict__ wv_adj,
    const float* __restrict__ wq_pt,  const float* __restrict__ wk_pt,  const float* __restrict__ wv_pt,
    const float* __restrict__ wq_cst, const float* __restrict__ wk_cst, const float* __restrict__ wv_cst,
    const int* __restrict__ fps_idx, const int* __restrict__ nbr_idx,
    float* __restrict__ out)
{
    __shared__ float s_cf[CIN];
    __shared__ float s_q[CO];
    __shared__ float s_u[136];
    __shared__ float s_fea[KNN][136];
    __shared__ float s_sc[KNN];
    __shared__ float s_caux[4];
    __shared__ float s_wf[136];
    __shared__ int   s_nbr[KNN];

    const int bs = blockIdx.x;
    const int b  = bs >> 10;
    const int t  = threadIdx.x;
    const int ci = fps_idx[bs];

    if (t < KNN) s_nbr[t] = nbr_idx[bs*KNN + t];
    // center gathers (small outputs)
    if (t < 3)                 out[OFF_CXYZ + bs*3 + t]      = xyz[(size_t)(b*NPTS+ci)*3 + t];
    if (t >= 64 && t < 67)     out[OFF_CMAD + bs*3 + (t-64)] = mad[(size_t)(b*NPTS+ci)*3 + (t-64)];
    if (t >= 96 && t < 98)     out[OFF_CADJ + bs*2 + (t-96)] = adj[(size_t)(b*NPTS+ci)*2 + (t-96)];
    if (t >= 128 && t < 132)   out[OFF_CPT  + bs*4 + (t-128)] = pt[(size_t)(b*NPTS+ci)*4 + (t-128)];
    __syncthreads();

    attn_type<0>(b, bs, ci, mad_fea, mad, wq_mad, wk_mad, wv_mad, out + OFF_OMAD,
                 s_cf, s_q, s_u, s_fea, s_sc, s_caux, s_wf, s_nbr);
    attn_type<1>(b, bs, ci, adj_fea, adj, wq_adj, wk_adj, wv_adj, out + OFF_OADJ,
                 s_cf, s_q, s_u, s_fea, s_sc, s_caux, s_wf, s_nbr);
    attn_type<2>(b, bs, ci, pt_fea,  pt,  wq_pt,  wk_pt,  wv_pt,  out + OFF_OPT,
                 s_cf, s_q, s_u, s_fea, s_sc, s_caux, s_wf, s_nbr);
    attn_type<3>(b, bs, ci, cst_fea, xyz, wq_cst, wk_cst, wv_cst, out + OFF_OCST,
                 s_cf, s_q, s_u, s_fea, s_sc, s_caux, s_wf, s_nbr);
}

extern "C" void kernel_launch(void* const* d_in, const int* in_sizes, int n_in,
                              void* d_out, int out_size, void* d_ws, size_t ws_size,
                              hipStream_t stream)
{
    const float* xyz     = (const float*)d_in[0];
    const float* mad     = (const float*)d_in[1];
    const float* adj     = (const float*)d_in[2];
    const float* pt      = (const float*)d_in[3];
    const float* mad_fea = (const float*)d_in[4];
    const float* adj_fea = (const float*)d_in[5];
    const float* pt_fea  = (const float*)d_in[6];
    const float* cst_fea = (const float*)d_in[7];
    const float* wq_mad  = (const float*)d_in[8];
    const float* wk_mad  = (const float*)d_in[9];
    const float* wv_mad  = (const float*)d_in[10];
    const float* wq_adj  = (const float*)d_in[11];
    const float* wk_adj  = (const float*)d_in[12];
    const float* wv_adj  = (const float*)d_in[13];
    const float* wq_pt   = (const float*)d_in[14];
    const float* wk_pt   = (const float*)d_in[15];
    const float* wv_pt   = (const float*)d_in[16];
    const float* wq_cst  = (const float*)d_in[17];
    const float* wk_cst  = (const float*)d_in[18];
    const float* wv_cst  = (const float*)d_in[19];
    float* out = (float*)d_out;

    int* fps_idx = (int*)d_ws;                      // BATCH*NC ints
    int* nbr_idx = fps_idx + BATCH*NC;              // BATCH*NC*KNN ints

    fps_kernel<<<BATCH, 256, 0, stream>>>(xyz, fps_idx);
    knn_kernel<<<BATCH*NC, 256, 0, stream>>>(xyz, fps_idx, nbr_idx);
    attn_kernel<<<BATCH*NC, 256, 0, stream>>>(xyz, mad, adj, pt,
        mad_fea, adj_fea, pt_fea, cst_fea,
        wq_mad, wk_mad, wv_mad, wq_adj, wk_adj, wv_adj,
        wq_pt, wk_pt, wv_pt, wq_cst, wk_cst, wv_cst,
        fps_idx, nbr_idx, out);
}

// Round 3
// 1550.207 us; speedup vs baseline: 1.8709x; 1.1494x over previous
//
#include <hip/hip_runtime.h>

#define BATCH 4
#define NPTS  4096
#define NC    1024
#define KNN   32
#define CIN   128
#define CO    256

// output layout (flat f32, reference return order)
#define OFF_CXYZ 0
#define OFF_CMAD (BATCH*NC*3)                 // 12288
#define OFF_CADJ (OFF_CMAD + BATCH*NC*3)     // 24576
#define OFF_CPT  (OFF_CADJ + BATCH*NC*2)     // 32768
#define OFF_OMAD (OFF_CPT  + BATCH*NC*4)     // 49152
#define OFF_OADJ (OFF_OMAD + BATCH*NC*CO)
#define OFF_OPT  (OFF_OADJ + BATCH*NC*CO)
#define OFF_OCST (OFF_OPT  + BATCH*NC*CO)

// ---------------------------------------------------------------------------
// DPP wave-64 (value,index) reduction — VALU pipe, not LDS.
// row_shr 1/2/4/8 within rows of 16, then row_bcast15 + row_bcast31.
// Result lands in lane 63. Invalid source lanes receive the identity via
// the `old` operand (bound_ctrl=false, masks 0xf).
// ---------------------------------------------------------------------------
template<int CTRL, bool MAXI>
__device__ __forceinline__ void dpp_combine(float& v, int& i, float idv, int idi)
{
    int pv = __builtin_amdgcn_update_dpp(__float_as_int(idv), __float_as_int(v),
                                         CTRL, 0xf, 0xf, false);
    int pi = __builtin_amdgcn_update_dpp(idi, i, CTRL, 0xf, 0xf, false);
    float fv = __int_as_float(pv);
    bool better = MAXI ? (fv > v || (fv == v && pi < i))
                       : (fv < v || (fv == v && pi < i));
    if (better) { v = fv; i = pi; }
}

template<bool MAXI>
__device__ __forceinline__ void wave_reduce_pair(float& bv, int& bi)
{
    const float idv = MAXI ? -1.0f : 3.0e38f;
    const int   idi = 0x7fffffff;
    dpp_combine<0x111, MAXI>(bv, bi, idv, idi);  // row_shr:1
    dpp_combine<0x112, MAXI>(bv, bi, idv, idi);  // row_shr:2
    dpp_combine<0x114, MAXI>(bv, bi, idv, idi);  // row_shr:4
    dpp_combine<0x118, MAXI>(bv, bi, idv, idi);  // row_shr:8
    dpp_combine<0x142, MAXI>(bv, bi, idv, idi);  // row_bcast:15
    dpp_combine<0x143, MAXI>(bv, bi, idv, idi);  // row_bcast:31
    // lane 63 now holds the wave's (best value, best index)
}

// ---------------------------------------------------------------------------
// FPS: one block per batch, 256 threads x 16 points in REGISTERS.
// One barrier per iteration; DPP intra-wave reduce; double-buffered LDS for
// the 4 wave candidates; all threads redundantly pick the winner.
// Exact np f32 op order via _rn intrinsics; argmax lowest-index tie-break.
// ---------------------------------------------------------------------------
__global__ __launch_bounds__(256) void fps_kernel(const float* __restrict__ xyz,
                                                  int* __restrict__ fps_idx)
{
    const int b = blockIdx.x;
    const int t = threadIdx.x;
    const float* xb = xyz + (size_t)b * NPTS * 3;

    __shared__ float4 s_xyz[NPTS];          // 64 KB
    __shared__ float  s_cv[2][4];
    __shared__ int    s_ci[2][4];

    float px[16], py[16], pz[16], dd[16];
#pragma unroll
    for (int i = 0; i < 16; ++i) {
        int p = t + i * 256;
        px[i] = xb[p*3+0]; py[i] = xb[p*3+1]; pz[i] = xb[p*3+2];
        s_xyz[p] = make_float4(px[i], py[i], pz[i], 0.f);
        dd[i] = 1e10f;
    }
    __syncthreads();

    int far = 0;
    for (int s = 0; s < NC; ++s) {
        if (t == 0) fps_idx[b*NC + s] = far;
        const float4 c = s_xyz[far];
        float bv = -1.0f; int bi = 0x7fffffff;
#pragma unroll
        for (int i = 0; i < 16; ++i) {
            float dx = __fsub_rn(px[i], c.x);
            float dy = __fsub_rn(py[i], c.y);
            float dz = __fsub_rn(pz[i], c.z);
            float d  = __fadd_rn(__fadd_rn(__fmul_rn(dx,dx), __fmul_rn(dy,dy)), __fmul_rn(dz,dz));
            float nd = fminf(dd[i], d);
            dd[i] = nd;
            if (nd > bv) { bv = nd; bi = t + i*256; }   // ascending p => lowest idx on tie
        }
        wave_reduce_pair<true>(bv, bi);
        const int buf = s & 1;
        if ((t & 63) == 63) { s_cv[buf][t>>6] = bv; s_ci[buf][t>>6] = bi; }
        __syncthreads();
        float v = s_cv[buf][0]; int w = s_ci[buf][0];
#pragma unroll
        for (int r = 1; r < 4; ++r) {
            float rv = s_cv[buf][r]; int ri = s_ci[buf][r];
            if (rv > v || (rv == v && ri < w)) { v = rv; w = ri; }
        }
        far = w;
    }
}

// ---------------------------------------------------------------------------
// kNN for the selected centers only. One block per (b,s), 256 threads,
// 16 distances per thread in REGISTERS. 32 selection passes, one barrier
// each; DPP intra-wave reduce; removal via unrolled compare (NO dynamic
// register indexing -> no scratch). Reference distance formula, np op
// order; lowest-index tie-break.
// ---------------------------------------------------------------------------
__global__ __launch_bounds__(256) void knn_kernel(const float* __restrict__ xyz,
                                                  const int* __restrict__ fps_idx,
                                                  int* __restrict__ nbr_idx)
{
    const int bs = blockIdx.x;
    const int b  = bs >> 10;
    const int t  = threadIdx.x;
    const float* xb = xyz + (size_t)b * NPTS * 3;
    const int ci = fps_idx[bs];
    const float cx = xb[ci*3], cy = xb[ci*3+1], cz = xb[ci*3+2];
    const float sqc = __fadd_rn(__fadd_rn(__fmul_rn(cx,cx), __fmul_rn(cy,cy)), __fmul_rn(cz,cz));

    float rd[16];
#pragma unroll
    for (int i = 0; i < 16; ++i) {
        int p = t + i * 256;
        float x = xb[p*3], y = xb[p*3+1], z = xb[p*3+2];
        float sqm = __fadd_rn(__fadd_rn(__fmul_rn(x,x), __fmul_rn(y,y)), __fmul_rn(z,z));
        float dot = __fadd_rn(__fadd_rn(__fmul_rn(cx,x), __fmul_rn(cy,y)), __fmul_rn(cz,z));
        rd[i] = __fsub_rn(__fadd_rn(sqc, sqm), __fmul_rn(2.0f, dot));
    }

    __shared__ float s_cv[2][4];
    __shared__ int   s_ci[2][4];

    for (int kk = 0; kk < KNN; ++kk) {
        float bv = 3.0e38f; int bi = 0x7fffffff;
#pragma unroll
        for (int i = 0; i < 16; ++i) {
            float vv = rd[i];
            if (vv < bv) { bv = vv; bi = t + i*256; }   // ascending p => lowest idx on tie
        }
        wave_reduce_pair<false>(bv, bi);
        const int buf = kk & 1;
        if ((t & 63) == 63) { s_cv[buf][t>>6] = bv; s_ci[buf][t>>6] = bi; }
        __syncthreads();
        float v = s_cv[buf][0]; int w = s_ci[buf][0];
#pragma unroll
        for (int r = 1; r < 4; ++r) {
            float rv = s_cv[buf][r]; int ri = s_ci[buf][r];
            if (rv < v || (rv == v && ri < w)) { v = rv; w = ri; }
        }
        if (t == 0) nbr_idx[bs*KNN + kk] = w;
#pragma unroll
        for (int i = 0; i < 16; ++i)                      // static indexing only
            if (w == t + i*256) rd[i] = 3.0e38f;
    }
}

// ---------------------------------------------------------------------------
// Factorized attention: scores = (Wk·q)·fea, o = Wv^T·(sum_k attn_k fea_k).
// One block per (b,s), 256 threads. TYPE: 0=mad 1=adj 2=pt 3=cst.
// ---------------------------------------------------------------------------
template<int TYPE>
__device__ __forceinline__ void attn_type(
    int b, int bs, int ci,
    const float* __restrict__ fea, const float* __restrict__ aux,
    const float* __restrict__ Wq, const float* __restrict__ Wk, const float* __restrict__ Wv,
    float* __restrict__ outp,
    float* s_cf, float* s_q, float* s_u, float (*s_fea)[136],
    float* s_sc, float* s_caux, float* s_wf, const int* s_nbr)
{
    constexpr int D    = (TYPE==2) ? 136 : (TYPE==1) ? 132 : 131;
    constexpr int AUXC = (TYPE==2) ? 4   : (TYPE==1) ? 2   : 3;
    const int t = threadIdx.x;
    const int g = t >> 5, l = t & 31;

    // center feature + center aux
    if (t < CIN) s_cf[t] = fea[(size_t)(b*NPTS + ci)*CIN + t];
    if (t >= CIN && t < CIN + AUXC) s_caux[t-CIN] = aux[(size_t)(b*NPTS + ci)*AUXC + (t-CIN)];
    __syncthreads();

    // q_h = sum_c cf[c] * Wq[c,h]
    float q = 0.f;
#pragma unroll 16
    for (int c = 0; c < CIN; ++c) q = fmaf(s_cf[c], Wq[c*CO + t], q);
    s_q[t] = q;
    __syncthreads();

    // u_d = sum_h Wk[d,h] * q[h]   (8 half-wave groups, coalesced Wk rows)
    for (int d0 = 0; d0 < D; d0 += 8) {
        int d = d0 + g;
        float acc = 0.f;
        if (d < D) {
            const float* wrow = Wk + (size_t)d * CO;
#pragma unroll
            for (int h = l; h < CO; h += 32) acc = fmaf(wrow[h], s_q[h], acc);
        }
#pragma unroll
        for (int off = 16; off; off >>= 1) acc += __shfl_xor(acc, off);
        if (l == 0 && d < D) s_u[d] = acc;
    }

    // gather all 32 neighbor features (+ aux concat) into LDS
    for (int i = t; i < KNN*CIN; i += 256) {
        int kk = i >> 7, c = i & 127;
        s_fea[kk][c] = fea[(size_t)(b*NPTS + s_nbr[kk])*CIN + c];
    }
    if (t < KNN) {
        int j = s_nbr[t];
        if (TYPE == 0 || TYPE == 3) {
#pragma unroll
            for (int i2 = 0; i2 < 3; ++i2)
                s_fea[t][CIN+i2] = aux[(size_t)(b*NPTS + j)*3 + i2] - s_caux[i2];
        } else if (TYPE == 1) {
            s_fea[t][CIN+0] = aux[(size_t)(b*NPTS + j)*2 + 0];
            s_fea[t][CIN+1] = aux[(size_t)(b*NPTS + j)*2 + 1];
            s_fea[t][CIN+2] = s_caux[0];
            s_fea[t][CIN+3] = s_caux[1];
        } else {
#pragma unroll
            for (int i2 = 0; i2 < 4; ++i2) s_fea[t][CIN+i2]   = aux[(size_t)(b*NPTS + j)*4 + i2];
#pragma unroll
            for (int i2 = 0; i2 < 4; ++i2) s_fea[t][CIN+4+i2] = s_caux[i2];
        }
    }
    __syncthreads();

    // scores_k = (u . fea_k) / 16
#pragma unroll
    for (int it = 0; it < 4; ++it) {
        int kk = it*8 + g;
        float acc = 0.f;
        for (int d = l; d < D; d += 32) acc = fmaf(s_fea[kk][d], s_u[d], acc);
#pragma unroll
        for (int off = 16; off; off >>= 1) acc += __shfl_xor(acc, off);
        if (l == 0) s_sc[kk] = acc * 0.0625f;
    }
    __syncthreads();

    // softmax over 32 (lanes 0..31 of wave 0)
    if (t < KNN) {
        float sc = s_sc[t];
        float m = sc;
#pragma unroll
        for (int off = 16; off; off >>= 1) m = fmaxf(m, __shfl_xor(m, off));
        float e = expf(sc - m);
        float ssum = e;
#pragma unroll
        for (int off = 16; off; off >>= 1) ssum += __shfl_xor(ssum, off);
        s_sc[t] = e / ssum;
    }
    __syncthreads();

    // wfea_d = sum_k attn_k * fea_k[d]
    if (t < D) {
        float wf = 0.f;
#pragma unroll
        for (int kk = 0; kk < KNN; ++kk) wf = fmaf(s_sc[kk], s_fea[kk][t], wf);
        s_wf[t] = wf;
    }
    __syncthreads();

    // o_h = sum_d wfea_d * Wv[d,h]
    float o = 0.f;
#pragma unroll 8
    for (int d = 0; d < D; ++d) o = fmaf(s_wf[d], Wv[(size_t)d*CO + t], o);
    outp[(size_t)bs*CO + t] = o;
    __syncthreads();
}

__global__ __launch_bounds__(256) void attn_kernel(
    const float* __restrict__ xyz, const float* __restrict__ mad,
    const float* __restrict__ adj, const float* __restrict__ pt,
    const float* __restrict__ mad_fea, const float* __restrict__ adj_fea,
    const float* __restrict__ pt_fea,  const float* __restrict__ cst_fea,
    const float* __restrict__ wq_mad, const float* __restrict__ wk_mad, const float* __restrict__ wv_mad,
    const float* __restrict__ wq_adj, const float* __restrict__ wk_adj, const float* __restrict__ wv_adj,
    const float* __restrict__ wq_pt,  const float* __restrict__ wk_pt,  const float* __restrict__ wv_pt,
    const float* __restrict__ wq_cst, const float* __restrict__ wk_cst, const float* __restrict__ wv_cst,
    const int* __restrict__ fps_idx, const int* __restrict__ nbr_idx,
    float* __restrict__ out)
{
    __shared__ float s_cf[CIN];
    __shared__ float s_q[CO];
    __shared__ float s_u[136];
    __shared__ float s_fea[KNN][136];
    __shared__ float s_sc[KNN];
    __shared__ float s_caux[4];
    __shared__ float s_wf[136];
    __shared__ int   s_nbr[KNN];

    const int bs = blockIdx.x;
    const int b  = bs >> 10;
    const int t  = threadIdx.x;
    const int ci = fps_idx[bs];

    if (t < KNN) s_nbr[t] = nbr_idx[bs*KNN + t];
    // center gathers (small outputs)
    if (t < 3)                 out[OFF_CXYZ + bs*3 + t]      = xyz[(size_t)(b*NPTS+ci)*3 + t];
    if (t >= 64 && t < 67)     out[OFF_CMAD + bs*3 + (t-64)] = mad[(size_t)(b*NPTS+ci)*3 + (t-64)];
    if (t >= 96 && t < 98)     out[OFF_CADJ + bs*2 + (t-96)] = adj[(size_t)(b*NPTS+ci)*2 + (t-96)];
    if (t >= 128 && t < 132)   out[OFF_CPT  + bs*4 + (t-128)] = pt[(size_t)(b*NPTS+ci)*4 + (t-128)];
    __syncthreads();

    attn_type<0>(b, bs, ci, mad_fea, mad, wq_mad, wk_mad, wv_mad, out + OFF_OMAD,
                 s_cf, s_q, s_u, s_fea, s_sc, s_caux, s_wf, s_nbr);
    attn_type<1>(b, bs, ci, adj_fea, adj, wq_adj, wk_adj, wv_adj, out + OFF_OADJ,
                 s_cf, s_q, s_u, s_fea, s_sc, s_caux, s_wf, s_nbr);
    attn_type<2>(b, bs, ci, pt_fea,  pt,  wq_pt,  wk_pt,  wv_pt,  out + OFF_OPT,
                 s_cf, s_q, s_u, s_fea, s_sc, s_caux, s_wf, s_nbr);
    attn_type<3>(b, bs, ci, cst_fea, xyz, wq_cst, wk_cst, wv_cst, out + OFF_OCST,
                 s_cf, s_q, s_u, s_fea, s_sc, s_caux, s_wf, s_nbr);
}

extern "C" void kernel_launch(void* const* d_in, const int* in_sizes, int n_in,
                              void* d_out, int out_size, void* d_ws, size_t ws_size,
                              hipStream_t stream)
{
    const float* xyz     = (const float*)d_in[0];
    const float* mad     = (const float*)d_in[1];
    const float* adj     = (const float*)d_in[2];
    const float* pt      = (const float*)d_in[3];
    const float* mad_fea = (const float*)d_in[4];
    const float* adj_fea = (const float*)d_in[5];
    const float* pt_fea  = (const float*)d_in[6];
    const float* cst_fea = (const float*)d_in[7];
    const float* wq_mad  = (const float*)d_in[8];
    const float* wk_mad  = (const float*)d_in[9];
    const float* wv_mad  = (const float*)d_in[10];
    const float* wq_adj  = (const float*)d_in[11];
    const float* wk_adj  = (const float*)d_in[12];
    const float* wv_adj  = (const float*)d_in[13];
    const float* wq_pt   = (const float*)d_in[14];
    const float* wk_pt   = (const float*)d_in[15];
    const float* wv_pt   = (const float*)d_in[16];
    const float* wq_cst  = (const float*)d_in[17];
    const float* wk_cst  = (const float*)d_in[18];
    const float* wv_cst  = (const float*)d_in[19];
    float* out = (float*)d_out;

    int* fps_idx = (int*)d_ws;                      // BATCH*NC ints
    int* nbr_idx = fps_idx + BATCH*NC;              // BATCH*NC*KNN ints

    fps_kernel<<<BATCH, 256, 0, stream>>>(xyz, fps_idx);
    knn_kernel<<<BATCH*NC, 256, 0, stream>>>(xyz, fps_idx, nbr_idx);
    attn_kernel<<<BATCH*NC, 256, 0, stream>>>(xyz, mad, adj, pt,
        mad_fea, adj_fea, pt_fea, cst_fea,
        wq_mad, wk_mad, wv_mad, wq_adj, wk_adj, wv_adj,
        wq_pt, wk_pt, wv_pt, wq_cst, wk_cst, wv_cst,
        fps_idx, nbr_idx, out);
}

// Round 4
// 1153.216 us; speedup vs baseline: 2.5149x; 1.3442x over previous
//
#include <hip/hip_runtime.h>

#define BATCH 4
#define NPTS  4096
#define NC    1024
#define KNN   32
#define CIN   128
#define CO    256

// output layout (flat f32, reference return order)
#define OFF_CXYZ 0
#define OFF_CMAD (BATCH*NC*3)
#define OFF_CADJ (OFF_CMAD + BATCH*NC*3)
#define OFF_CPT  (OFF_CADJ + BATCH*NC*2)
#define OFF_OMAD (OFF_CPT  + BATCH*NC*4)
#define OFF_OADJ (OFF_OMAD + BATCH*NC*CO)
#define OFF_OPT  (OFF_OADJ + BATCH*NC*CO)
#define OFF_OCST (OFF_OPT  + BATCH*NC*CO)

typedef unsigned long long u64;

// ---------------------------------------------------------------------------
// u64 wave-64 reduce via DPP (VALU pipe). row_shr 1/2/4/8 + row_bcast 15/31.
// Result in lane 63. MAXI: max (identity 0), else min (identity ~0).
// ---------------------------------------------------------------------------
template<bool MAXI>
__device__ __forceinline__ u64 wave_red_u64(u64 k)
{
    const int oldv = MAXI ? 0 : -1;
#define DPP_STEP(C)                                                              \
    {                                                                            \
        unsigned plo = (unsigned)__builtin_amdgcn_update_dpp(oldv, (int)(unsigned)k,        C, 0xf, 0xf, false); \
        unsigned phi = (unsigned)__builtin_amdgcn_update_dpp(oldv, (int)(unsigned)(k>>32),  C, 0xf, 0xf, false); \
        u64 p = ((u64)phi << 32) | plo;                                          \
        if (MAXI ? (p > k) : (p < k)) k = p;                                     \
    }
    DPP_STEP(0x111) DPP_STEP(0x112) DPP_STEP(0x114)
    DPP_STEP(0x118) DPP_STEP(0x142) DPP_STEP(0x143)
#undef DPP_STEP
    return k;
}

// ---------------------------------------------------------------------------
// FPS: one block per batch, 256 threads x 16 points in registers.
// Key = (float_bits(dist) << 32) | ~idx  (dist >= 0 so bits are monotonic;
// ~idx makes lower index win ties under max). Depth-4 tree + DPP + one u64
// candidate per wave in LDS. Exact np f32 op order via _rn intrinsics.
// ---------------------------------------------------------------------------
__global__ __launch_bounds__(256) void fps_kernel(const float* __restrict__ xyz,
                                                  int* __restrict__ fps_idx)
{
    const int b = blockIdx.x;
    const int t = threadIdx.x;
    const float* xb = xyz + (size_t)b * NPTS * 3;

    __shared__ float4 s_xyz[NPTS];          // 64 KB
    __shared__ u64    s_ck[2][4];

    float px[16], py[16], pz[16], dd[16];
    unsigned inv[16];
#pragma unroll
    for (int i = 0; i < 16; ++i) {
        int p = t + i * 256;
        px[i] = xb[p*3+0]; py[i] = xb[p*3+1]; pz[i] = xb[p*3+2];
        s_xyz[p] = make_float4(px[i], py[i], pz[i], 0.f);
        dd[i] = 1e10f;
        inv[i] = ~(unsigned)p;
    }
    __syncthreads();

    int far = 0;
    float cx = xb[0], cy = xb[1], cz = xb[2];
    for (int s = 0; s < NC; ++s) {
        if (t == 0) fps_idx[b*NC + s] = far;
        u64 K[16];
#pragma unroll
        for (int i = 0; i < 16; ++i) {
            float dx = __fsub_rn(px[i], cx);
            float dy = __fsub_rn(py[i], cy);
            float dz = __fsub_rn(pz[i], cz);
            float d  = __fadd_rn(__fadd_rn(__fmul_rn(dx,dx), __fmul_rn(dy,dy)), __fmul_rn(dz,dz));
            float nd = fminf(dd[i], d);
            dd[i] = nd;
            K[i] = ((u64)__float_as_uint(nd) << 32) | inv[i];
        }
#pragma unroll
        for (int st = 8; st >= 1; st >>= 1)
#pragma unroll
            for (int j = 0; j < st; ++j)
                if (K[j+st] > K[j]) K[j] = K[j+st];
        u64 k = wave_red_u64<true>(K[0]);

        const int buf = s & 1;
        if ((t & 63) == 63) s_ck[buf][t>>6] = k;
        __syncthreads();
        u64 k0 = s_ck[buf][0], k1 = s_ck[buf][1], k2 = s_ck[buf][2], k3 = s_ck[buf][3];
        if (k1 > k0) k0 = k1;
        if (k3 > k2) k2 = k3;
        if (k2 > k0) k0 = k2;
        far = (int)~((unsigned)k0);
        float4 c = s_xyz[far];
        cx = c.x; cy = c.y; cz = c.z;
    }
}

// ---------------------------------------------------------------------------
// kNN at selected centers. One block per (b,s), 256 threads, 16 dists/thread.
// Keys packed ONCE (sign-flip trick handles possible tiny negatives exactly
// in float order); 32 passes of tree+DPP+single-u64-per-wave; removal sets
// the owner's key to ~0. Reference formula, np op order; lowest-index ties.
// ---------------------------------------------------------------------------
__global__ __launch_bounds__(256) void knn_kernel(const float* __restrict__ xyz,
                                                  const int* __restrict__ fps_idx,
                                                  int* __restrict__ nbr_idx)
{
    const int bs = blockIdx.x;
    const int b  = bs >> 10;
    const int t  = threadIdx.x;
    const float* xb = xyz + (size_t)b * NPTS * 3;
    const int ci = fps_idx[bs];
    const float cx = xb[ci*3], cy = xb[ci*3+1], cz = xb[ci*3+2];
    const float sqc = __fadd_rn(__fadd_rn(__fmul_rn(cx,cx), __fmul_rn(cy,cy)), __fmul_rn(cz,cz));

    u64 key[16];
#pragma unroll
    for (int i = 0; i < 16; ++i) {
        int p = t + i * 256;
        float x = xb[p*3], y = xb[p*3+1], z = xb[p*3+2];
        float sqm = __fadd_rn(__fadd_rn(__fmul_rn(x,x), __fmul_rn(y,y)), __fmul_rn(z,z));
        float dot = __fadd_rn(__fadd_rn(__fmul_rn(cx,x), __fmul_rn(cy,y)), __fmul_rn(cz,z));
        float dv  = __fsub_rn(__fadd_rn(sqc, sqm), __fmul_rn(2.0f, dot));
        unsigned u = __float_as_uint(dv);
        u ^= (unsigned)(((int)u >> 31)) | 0x80000000u;   // monotonic for all floats
        key[i] = ((u64)u << 32) | (unsigned)p;
    }

    __shared__ u64 s_ck[2][4];

    for (int kk = 0; kk < KNN; ++kk) {
        u64 K[16];
#pragma unroll
        for (int i = 0; i < 16; ++i) K[i] = key[i];
#pragma unroll
        for (int st = 8; st >= 1; st >>= 1)
#pragma unroll
            for (int j = 0; j < st; ++j)
                if (K[j+st] < K[j]) K[j] = K[j+st];
        u64 k = wave_red_u64<false>(K[0]);

        const int buf = kk & 1;
        if ((t & 63) == 63) s_ck[buf][t>>6] = k;
        __syncthreads();
        u64 k0 = s_ck[buf][0], k1 = s_ck[buf][1], k2 = s_ck[buf][2], k3 = s_ck[buf][3];
        if (k1 < k0) k0 = k1;
        if (k3 < k2) k2 = k3;
        if (k2 < k0) k0 = k2;
        unsigned w = (unsigned)k0;
        if (t == 0) nbr_idx[bs*KNN + kk] = (int)w;
#pragma unroll
        for (int i = 0; i < 16; ++i)
            if (w == (unsigned)(t + i*256)) key[i] = ~0ull;
    }
}

// ---------------------------------------------------------------------------
// Factorized attention, G=4 centers per block: weights are read ONCE per
// block and feed 4 accumulators in each phase. Per-center math (op order)
// identical to the verified single-center version.
// ---------------------------------------------------------------------------
template<int TYPE>
__device__ __forceinline__ void attn_type4(
    int b, int bs0,
    const float* __restrict__ fea, const float* __restrict__ aux,
    const float* __restrict__ Wq, const float* __restrict__ Wk, const float* __restrict__ Wv,
    float* __restrict__ outp,
    float (*s_cf)[CIN], float (*s_q)[CO], float (*s_u)[136], float (*s_fea)[KNN][136],
    float (*s_sc)[KNN], float (*s_caux)[4], float (*s_wf)[136],
    const int (*s_nbr)[KNN], const int* s_ci4)
{
    constexpr int D    = (TYPE==2) ? 136 : (TYPE==1) ? 132 : 131;
    constexpr int AUXC = (TYPE==2) ? 4   : (TYPE==1) ? 2   : 3;
    const int t = threadIdx.x;
    const int g32 = t >> 5, l = t & 31;

    // center features (4 x 128) + center aux
    {
        int i0 = t, i1 = t + 256;
        s_cf[i0>>7][i0&127] = fea[(size_t)(b*NPTS + s_ci4[i0>>7])*CIN + (i0&127)];
        s_cf[i1>>7][i1&127] = fea[(size_t)(b*NPTS + s_ci4[i1>>7])*CIN + (i1&127)];
    }
    if (t < 16 && (t&3) < AUXC)
        s_caux[t>>2][t&3] = aux[(size_t)(b*NPTS + s_ci4[t>>2])*AUXC + (t&3)];
    __syncthreads();

    // q[g][t] = sum_c cf[g][c] * Wq[c][t]   (Wq row read once, 4 FMAs)
    float q0=0.f, q1=0.f, q2=0.f, q3=0.f;
#pragma unroll 8
    for (int c = 0; c < CIN; ++c) {
        float w = Wq[c*CO + t];
        q0 = fmaf(s_cf[0][c], w, q0); q1 = fmaf(s_cf[1][c], w, q1);
        q2 = fmaf(s_cf[2][c], w, q2); q3 = fmaf(s_cf[3][c], w, q3);
    }
    s_q[0][t]=q0; s_q[1][t]=q1; s_q[2][t]=q2; s_q[3][t]=q3;
    __syncthreads();

    // u[g][d] = sum_h Wk[d][h] * q[g][h]   (8 lane-groups of 32; Wk once)
    for (int d0 = 0; d0 < D; d0 += 8) {
        int d = d0 + g32;
        float a0=0.f, a1=0.f, a2=0.f, a3=0.f;
        if (d < D) {
            const float* wr = Wk + (size_t)d * CO;
#pragma unroll
            for (int h = l; h < CO; h += 32) {
                float w = wr[h];
                a0 = fmaf(w, s_q[0][h], a0); a1 = fmaf(w, s_q[1][h], a1);
                a2 = fmaf(w, s_q[2][h], a2); a3 = fmaf(w, s_q[3][h], a3);
            }
        }
#pragma unroll
        for (int off = 16; off; off >>= 1) {
            a0 += __shfl_xor(a0, off); a1 += __shfl_xor(a1, off);
            a2 += __shfl_xor(a2, off); a3 += __shfl_xor(a3, off);
        }
        if (l == 0 && d < D) { s_u[0][d]=a0; s_u[1][d]=a1; s_u[2][d]=a2; s_u[3][d]=a3; }
    }

    // gather 4x32 neighbor feature rows (float4-vectorized)
#pragma unroll
    for (int j = 0; j < 16; ++j) {
        int i4 = t + j*256;                    // 0..4095
        int g = i4 >> 10, kk = (i4 >> 5) & 31, c4 = i4 & 31;
        const float4 v = *(const float4*)&fea[(size_t)(b*NPTS + s_nbr[g][kk])*CIN + c4*4];
        *(float4*)&s_fea[g][kk][c4*4] = v;
    }
    if (t < 128) {
        int g = t >> 5, kk = t & 31, j = s_nbr[g][kk];
        if (TYPE == 0 || TYPE == 3) {
#pragma unroll
            for (int i2 = 0; i2 < 3; ++i2)
                s_fea[g][kk][CIN+i2] = aux[(size_t)(b*NPTS + j)*3 + i2] - s_caux[g][i2];
        } else if (TYPE == 1) {
            s_fea[g][kk][CIN+0] = aux[(size_t)(b*NPTS + j)*2 + 0];
            s_fea[g][kk][CIN+1] = aux[(size_t)(b*NPTS + j)*2 + 1];
            s_fea[g][kk][CIN+2] = s_caux[g][0];
            s_fea[g][kk][CIN+3] = s_caux[g][1];
        } else {
#pragma unroll
            for (int i2 = 0; i2 < 4; ++i2) s_fea[g][kk][CIN+i2]   = aux[(size_t)(b*NPTS + j)*4 + i2];
#pragma unroll
            for (int i2 = 0; i2 < 4; ++i2) s_fea[g][kk][CIN+4+i2] = s_caux[g][i2];
        }
    }
    __syncthreads();

    // scores[g][k] = (u[g] . fea[g][k]) / 16   (128 dots, 8 lane-groups)
#pragma unroll
    for (int it = 0; it < 16; ++it) {
        int idx = it*8 + g32;
        int g = idx >> 5, kk = idx & 31;
        float acc = 0.f;
        for (int d = l; d < D; d += 32) acc = fmaf(s_fea[g][kk][d], s_u[g][d], acc);
#pragma unroll
        for (int off = 16; off; off >>= 1) acc += __shfl_xor(acc, off);
        if (l == 0) s_sc[g][kk] = acc * 0.0625f;
    }
    __syncthreads();

    // softmax over 32 per center (32-lane halves; offs <=16 stay in half)
    if (t < 128) {
        int g = t >> 5, kk = t & 31;
        float sc = s_sc[g][kk];
        float m = sc;
#pragma unroll
        for (int off = 16; off; off >>= 1) m = fmaxf(m, __shfl_xor(m, off));
        float e = expf(sc - m);
        float ssum = e;
#pragma unroll
        for (int off = 16; off; off >>= 1) ssum += __shfl_xor(ssum, off);
        s_sc[g][kk] = e / ssum;
    }
    __syncthreads();

    // wfea[g][d] = sum_k attn[g][k] * fea[g][k][d]   (4 groups of 64 lanes)
    {
        int g = t >> 6, l64 = t & 63;
        for (int d = l64; d < D; d += 64) {
            float wf = 0.f;
#pragma unroll
            for (int kk = 0; kk < KNN; ++kk) wf = fmaf(s_sc[g][kk], s_fea[g][kk][d], wf);
            s_wf[g][d] = wf;
        }
    }
    __syncthreads();

    // o[g][t] = sum_d wfea[g][d] * Wv[d][t]   (Wv row read once, 4 FMAs)
    float o0=0.f, o1=0.f, o2=0.f, o3=0.f;
#pragma unroll 8
    for (int d = 0; d < D; ++d) {
        float w = Wv[(size_t)d*CO + t];
        o0 = fmaf(s_wf[0][d], w, o0); o1 = fmaf(s_wf[1][d], w, o1);
        o2 = fmaf(s_wf[2][d], w, o2); o3 = fmaf(s_wf[3][d], w, o3);
    }
    outp[(size_t)(bs0+0)*CO + t] = o0;
    outp[(size_t)(bs0+1)*CO + t] = o1;
    outp[(size_t)(bs0+2)*CO + t] = o2;
    outp[(size_t)(bs0+3)*CO + t] = o3;
    __syncthreads();
}

__global__ __launch_bounds__(256) void attn_kernel(
    const float* __restrict__ xyz, const float* __restrict__ mad,
    const float* __restrict__ adj, const float* __restrict__ pt,
    const float* __restrict__ mad_fea, const float* __restrict__ adj_fea,
    const float* __restrict__ pt_fea,  const float* __restrict__ cst_fea,
    const float* __restrict__ wq_mad, const float* __restrict__ wk_mad, const float* __restrict__ wv_mad,
    const float* __restrict__ wq_adj, const float* __restrict__ wk_adj, const float* __restrict__ wv_adj,
    const float* __restrict__ wq_pt,  const float* __restrict__ wk_pt,  const float* __restrict__ wv_pt,
    const float* __restrict__ wq_cst, const float* __restrict__ wk_cst, const float* __restrict__ wv_cst,
    const int* __restrict__ fps_idx, const int* __restrict__ nbr_idx,
    float* __restrict__ out)
{
    __shared__ float s_cf[4][CIN];
    __shared__ float s_q[4][CO];
    __shared__ float s_u[4][136];
    __shared__ float s_fea[4][KNN][136];
    __shared__ float s_sc[4][KNN];
    __shared__ float s_caux[4][4];
    __shared__ float s_wf[4][136];
    __shared__ int   s_nbr[4][KNN];
    __shared__ int   s_ci4[4];

    const int bs0 = blockIdx.x * 4;
    const int b   = bs0 >> 10;
    const int t   = threadIdx.x;

    if (t < 4) s_ci4[t] = fps_idx[bs0 + t];
    if (t < 128) s_nbr[t>>5][t&31] = nbr_idx[(bs0 + (t>>5))*KNN + (t&31)];
    __syncthreads();

    // small per-center outputs: 4 groups of 64 lanes
    {
        int g = t >> 6, l64 = t & 63;
        int ci = s_ci4[g], bsg = bs0 + g;
        if (l64 < 3)              out[OFF_CXYZ + bsg*3 + l64]       = xyz[(size_t)(b*NPTS+ci)*3 + l64];
        if (l64 >= 4 && l64 < 7)  out[OFF_CMAD + bsg*3 + (l64-4)]   = mad[(size_t)(b*NPTS+ci)*3 + (l64-4)];
        if (l64 >= 8 && l64 < 10) out[OFF_CADJ + bsg*2 + (l64-8)]   = adj[(size_t)(b*NPTS+ci)*2 + (l64-8)];
        if (l64 >= 12 && l64 < 16)out[OFF_CPT  + bsg*4 + (l64-12)]  = pt[(size_t)(b*NPTS+ci)*4 + (l64-12)];
    }

    attn_type4<0>(b, bs0, mad_fea, mad, wq_mad, wk_mad, wv_mad, out + OFF_OMAD,
                  s_cf, s_q, s_u, s_fea, s_sc, s_caux, s_wf, s_nbr, s_ci4);
    attn_type4<1>(b, bs0, adj_fea, adj, wq_adj, wk_adj, wv_adj, out + OFF_OADJ,
                  s_cf, s_q, s_u, s_fea, s_sc, s_caux, s_wf, s_nbr, s_ci4);
    attn_type4<2>(b, bs0, pt_fea,  pt,  wq_pt,  wk_pt,  wv_pt,  out + OFF_OPT,
                  s_cf, s_q, s_u, s_fea, s_sc, s_caux, s_wf, s_nbr, s_ci4);
    attn_type4<3>(b, bs0, cst_fea, xyz, wq_cst, wk_cst, wv_cst, out + OFF_OCST,
                  s_cf, s_q, s_u, s_fea, s_sc, s_caux, s_wf, s_nbr, s_ci4);
}

extern "C" void kernel_launch(void* const* d_in, const int* in_sizes, int n_in,
                              void* d_out, int out_size, void* d_ws, size_t ws_size,
                              hipStream_t stream)
{
    const float* xyz     = (const float*)d_in[0];
    const float* mad     = (const float*)d_in[1];
    const float* adj     = (const float*)d_in[2];
    const float* pt      = (const float*)d_in[3];
    const float* mad_fea = (const float*)d_in[4];
    const float* adj_fea = (const float*)d_in[5];
    const float* pt_fea  = (const float*)d_in[6];
    const float* cst_fea = (const float*)d_in[7];
    const float* wq_mad  = (const float*)d_in[8];
    const float* wk_mad  = (const float*)d_in[9];
    const float* wv_mad  = (const float*)d_in[10];
    const float* wq_adj  = (const float*)d_in[11];
    const float* wk_adj  = (const float*)d_in[12];
    const float* wv_adj  = (const float*)d_in[13];
    const float* wq_pt   = (const float*)d_in[14];
    const float* wk_pt   = (const float*)d_in[15];
    const float* wv_pt   = (const float*)d_in[16];
    const float* wq_cst  = (const float*)d_in[17];
    const float* wk_cst  = (const float*)d_in[18];
    const float* wv_cst  = (const float*)d_in[19];
    float* out = (float*)d_out;

    int* fps_idx = (int*)d_ws;                      // BATCH*NC ints
    int* nbr_idx = fps_idx + BATCH*NC;              // BATCH*NC*KNN ints

    fps_kernel<<<BATCH, 256, 0, stream>>>(xyz, fps_idx);
    knn_kernel<<<BATCH*NC, 256, 0, stream>>>(xyz, fps_idx, nbr_idx);
    attn_kernel<<<BATCH*NC/4, 256, 0, stream>>>(xyz, mad, adj, pt,
        mad_fea, adj_fea, pt_fea, cst_fea,
        wq_mad, wk_mad, wv_mad, wq_adj, wk_adj, wv_adj,
        wq_pt, wk_pt, wv_pt, wq_cst, wk_cst, wv_cst,
        fps_idx, nbr_idx, out);
}

// Round 5
// 1120.068 us; speedup vs baseline: 2.5894x; 1.0296x over previous
//
#include <hip/hip_runtime.h>

#define BATCH 4
#define NPTS  4096
#define NC    1024
#define KNN   32
#define CIN   128
#define CO    256
#define DP    136   // padded feature dim (max over types); pad entries are exact zeros

// output layout (flat f32, reference return order)
#define OFF_CXYZ 0
#define OFF_CMAD (BATCH*NC*3)
#define OFF_CADJ (OFF_CMAD + BATCH*NC*3)
#define OFF_CPT  (OFF_CADJ + BATCH*NC*2)
#define OFF_OMAD (OFF_CPT  + BATCH*NC*4)
#define OFF_OADJ (OFF_OMAD + BATCH*NC*CO)
#define OFF_OPT  (OFF_OADJ + BATCH*NC*CO)
#define OFF_OCST (OFF_OPT  + BATCH*NC*CO)

typedef unsigned long long u64;

// ---------------------------------------------------------------------------
// u64 wave-64 reduce via DPP (VALU pipe). Result valid in lane 63.
// ---------------------------------------------------------------------------
template<bool MAXI>
__device__ __forceinline__ u64 wave_red_u64(u64 k)
{
    const int oldv = MAXI ? 0 : -1;
#define DPP_STEP(C)                                                              \
    {                                                                            \
        unsigned plo = (unsigned)__builtin_amdgcn_update_dpp(oldv, (int)(unsigned)k,        C, 0xf, 0xf, false); \
        unsigned phi = (unsigned)__builtin_amdgcn_update_dpp(oldv, (int)(unsigned)(k>>32),  C, 0xf, 0xf, false); \
        u64 p = ((u64)phi << 32) | plo;                                          \
        if (MAXI ? (p > k) : (p < k)) k = p;                                     \
    }
    DPP_STEP(0x111) DPP_STEP(0x112) DPP_STEP(0x114)
    DPP_STEP(0x118) DPP_STEP(0x142) DPP_STEP(0x143)
#undef DPP_STEP
    return k;
}

// ---------------------------------------------------------------------------
// Fused kernel: blocks 0..3 run FPS (unchanged from round 4); blocks 4..547
// precompute M[type] = Wq·Wk^T (zero-padded to 136 rows... cols) and the
// zero-padded Wvp[type]. Prep rides on the 252 CUs idle during FPS.
// ---------------------------------------------------------------------------
__global__ __launch_bounds__(256) void fps_prep_kernel(
    const float* __restrict__ xyz, int* __restrict__ fps_idx,
    const float* __restrict__ wq_mad, const float* __restrict__ wk_mad, const float* __restrict__ wv_mad,
    const float* __restrict__ wq_adj, const float* __restrict__ wk_adj, const float* __restrict__ wv_adj,
    const float* __restrict__ wq_pt,  const float* __restrict__ wk_pt,  const float* __restrict__ wv_pt,
    const float* __restrict__ wq_cst, const float* __restrict__ wk_cst, const float* __restrict__ wv_cst,
    float* __restrict__ M, float* __restrict__ Wvp)
{
    __shared__ float4 s_xyz[NPTS];          // 64 KB (prep reuses as scratch)
    __shared__ u64    s_ck[2][4];
    const int t = threadIdx.x;

    if (blockIdx.x >= BATCH) {
        // ---------------- prep path ----------------
        const int r    = blockIdx.x - BATCH;   // 0..4*DP-1
        const int type = r / DP;
        const int row  = r - type * DP;
        const float* wq; const float* wk; const float* wv; int D;
        if (type == 0)      { wq=wq_mad; wk=wk_mad; wv=wv_mad; D=131; }
        else if (type == 1) { wq=wq_adj; wk=wk_adj; wv=wv_adj; D=132; }
        else if (type == 2) { wq=wq_pt;  wk=wk_pt;  wv=wv_pt;  D=136; }
        else                { wq=wq_cst; wk=wk_cst; wv=wv_cst; D=131; }

        // zero-padded Wvp row
        Wvp[((size_t)type*DP + row)*CO + t] = (row < D) ? wv[(size_t)row*CO + t] : 0.f;

        // M[row][d] = sum_h Wq[row][h] * Wk[d][h]   (zero for d >= D)
        if (row < CIN) {
            float* sq = (float*)s_xyz;
            sq[t] = wq[(size_t)row*CO + t];
            __syncthreads();
            if (t < DP) {
                float acc = 0.f;
                if (t < D) {
                    const float* wkr = wk + (size_t)t * CO;
                    for (int h = 0; h < CO; h += 4) {
                        float4 a = *(const float4*)&wkr[h];
                        float4 b4 = *(const float4*)&sq[h];
                        acc = fmaf(a.x,b4.x,acc); acc = fmaf(a.y,b4.y,acc);
                        acc = fmaf(a.z,b4.z,acc); acc = fmaf(a.w,b4.w,acc);
                    }
                }
                M[((size_t)type*CIN + row)*DP + t] = acc;
            }
        }
        return;
    }

    // ---------------- FPS path (round-4 verified) ----------------
    const int b = blockIdx.x;
    const float* xb = xyz + (size_t)b * NPTS * 3;

    float px[16], py[16], pz[16], dd[16];
    unsigned inv[16];
#pragma unroll
    for (int i = 0; i < 16; ++i) {
        int p = t + i * 256;
        px[i] = xb[p*3+0]; py[i] = xb[p*3+1]; pz[i] = xb[p*3+2];
        s_xyz[p] = make_float4(px[i], py[i], pz[i], 0.f);
        dd[i] = 1e10f;
        inv[i] = ~(unsigned)p;
    }
    __syncthreads();

    int far = 0;
    float cx = xb[0], cy = xb[1], cz = xb[2];
    for (int s = 0; s < NC; ++s) {
        if (t == 0) fps_idx[b*NC + s] = far;
        u64 K[16];
#pragma unroll
        for (int i = 0; i < 16; ++i) {
            float dx = __fsub_rn(px[i], cx);
            float dy = __fsub_rn(py[i], cy);
            float dz = __fsub_rn(pz[i], cz);
            float d  = __fadd_rn(__fadd_rn(__fmul_rn(dx,dx), __fmul_rn(dy,dy)), __fmul_rn(dz,dz));
            float nd = fminf(dd[i], d);
            dd[i] = nd;
            K[i] = ((u64)__float_as_uint(nd) << 32) | inv[i];
        }
#pragma unroll
        for (int st = 8; st >= 1; st >>= 1)
#pragma unroll
            for (int j = 0; j < st; ++j)
                if (K[j+st] > K[j]) K[j] = K[j+st];
        u64 k = wave_red_u64<true>(K[0]);

        const int buf = s & 1;
        if ((t & 63) == 63) s_ck[buf][t>>6] = k;
        __syncthreads();
        u64 k0 = s_ck[buf][0], k1 = s_ck[buf][1], k2 = s_ck[buf][2], k3 = s_ck[buf][3];
        if (k1 > k0) k0 = k1;
        if (k3 > k2) k2 = k3;
        if (k2 > k0) k0 = k2;
        far = (int)~((unsigned)k0);
        float4 c = s_xyz[far];
        cx = c.x; cy = c.y; cz = c.z;
    }
}

// ---------------------------------------------------------------------------
// kNN with tournament caching: per-thread local min kept in a register; per
// pass only the cached minima are DPP-reduced; the winning thread (exec-
// masked branch, usually skipped per wave) clears its key and rescans its 16.
// Bit-exact vs reference (keys embed index; lowest-index tie-break).
// ---------------------------------------------------------------------------
__global__ __launch_bounds__(256) void knn_kernel(const float* __restrict__ xyz,
                                                  const int* __restrict__ fps_idx,
                                                  int* __restrict__ nbr_idx)
{
    const int bs = blockIdx.x;
    const int b  = bs >> 10;
    const int t  = threadIdx.x;
    const float* xb = xyz + (size_t)b * NPTS * 3;
    const int ci = fps_idx[bs];
    const float cx = xb[ci*3], cy = xb[ci*3+1], cz = xb[ci*3+2];
    const float sqc = __fadd_rn(__fadd_rn(__fmul_rn(cx,cx), __fmul_rn(cy,cy)), __fmul_rn(cz,cz));

    u64 key[16];
#pragma unroll
    for (int i = 0; i < 16; ++i) {
        int p = t + i * 256;
        float x = xb[p*3], y = xb[p*3+1], z = xb[p*3+2];
        float sqm = __fadd_rn(__fadd_rn(__fmul_rn(x,x), __fmul_rn(y,y)), __fmul_rn(z,z));
        float dot = __fadd_rn(__fadd_rn(__fmul_rn(cx,x), __fmul_rn(cy,y)), __fmul_rn(cz,z));
        float dv  = __fsub_rn(__fadd_rn(sqc, sqm), __fmul_rn(2.0f, dot));
        unsigned u = __float_as_uint(dv);
        u ^= (unsigned)(((int)u >> 31)) | 0x80000000u;   // order-monotonic for all floats
        key[i] = ((u64)u << 32) | (unsigned)p;
    }
    u64 kmin = key[0];
#pragma unroll
    for (int i = 1; i < 16; ++i) if (key[i] < kmin) kmin = key[i];

    __shared__ u64 s_ck[2][4];

    for (int kk = 0; kk < KNN; ++kk) {
        u64 k = wave_red_u64<false>(kmin);
        const int buf = kk & 1;
        if ((t & 63) == 63) s_ck[buf][t>>6] = k;
        __syncthreads();
        u64 k0 = s_ck[buf][0], k1 = s_ck[buf][1], k2 = s_ck[buf][2], k3 = s_ck[buf][3];
        if (k1 < k0) k0 = k1;
        if (k3 < k2) k2 = k3;
        if (k2 < k0) k0 = k2;
        unsigned w = (unsigned)k0;
        if (t == 0) nbr_idx[bs*KNN + kk] = (int)w;
        if ((w & 255u) == (unsigned)t) {          // only the owner thread
#pragma unroll
            for (int i = 0; i < 16; ++i)
                if (w == (unsigned)(t + i*256)) key[i] = ~0ull;
            u64 m = key[0];
#pragma unroll
            for (int i = 1; i < 16; ++i) if (key[i] < m) m = key[i];
            kmin = m;
        }
    }
}

// ---------------------------------------------------------------------------
// Attention with precomputed M = Wq·Wk^T and padded Wvp. Wave g owns center
// g: staging, u = cf·M, scores, softmax, wfea are all wave-private; only the
// o-phase (o = wf·Wvp, coalesced on h=t) crosses waves. All LDS reads f4.
// ---------------------------------------------------------------------------
template<int TYPE>
__device__ __forceinline__ void attn_t(
    int b, int bs0, int ci,
    const float* __restrict__ fea, const float* __restrict__ aux,
    const float* __restrict__ Mt, const float* __restrict__ Wvpt,
    float* __restrict__ outp,
    float (*s_cf)[CIN], float (*s_u)[DP], float (*s_fea)[KNN][DP],
    float (*s_sc)[KNN], float (*s_wf)[DP], const int (*s_nbr4)[KNN])
{
    const int t = threadIdx.x, g = t >> 6, l = t & 63;
    const int l31 = l & 31, h32 = l >> 5;

    // ---- stage (wave-private to center g) ----
    if (l < 32) {
        float4 v = *(const float4*)&fea[((size_t)(b*NPTS + ci))*CIN + l*4];
        *(float4*)&s_cf[g][l*4] = v;
    }
#pragma unroll
    for (int it = 0; it < 16; ++it) {
        int kk = it*2 + h32;
        int j  = s_nbr4[g][kk];
        float4 v = *(const float4*)&fea[((size_t)(b*NPTS + j))*CIN + l31*4];
        *(float4*)&s_fea[g][kk][l31*4] = v;
    }
    if (l < KNN) {
        int j = s_nbr4[g][l];
        float pad[8];
        if (TYPE == 0 || TYPE == 3) {
#pragma unroll
            for (int i = 0; i < 3; ++i)
                pad[i] = aux[(size_t)(b*NPTS + j)*3 + i] - aux[(size_t)(b*NPTS + ci)*3 + i];
            pad[3]=pad[4]=pad[5]=pad[6]=pad[7]=0.f;
        } else if (TYPE == 1) {
            pad[0] = aux[(size_t)(b*NPTS + j)*2 + 0];
            pad[1] = aux[(size_t)(b*NPTS + j)*2 + 1];
            pad[2] = aux[(size_t)(b*NPTS + ci)*2 + 0];
            pad[3] = aux[(size_t)(b*NPTS + ci)*2 + 1];
            pad[4]=pad[5]=pad[6]=pad[7]=0.f;
        } else {
#pragma unroll
            for (int i = 0; i < 4; ++i) pad[i]   = aux[(size_t)(b*NPTS + j)*4 + i];
#pragma unroll
            for (int i = 0; i < 4; ++i) pad[4+i] = aux[(size_t)(b*NPTS + ci)*4 + i];
        }
#pragma unroll
        for (int i = 0; i < 8; ++i) s_fea[g][l][CIN+i] = pad[i];
    }
    __syncthreads();

    // ---- u[g][d] = sum_c cf[g][c] * M[c][d]  (M coalesced, cf via b128) ----
#pragma unroll
    for (int j = 0; j < 3; ++j) {
        int d = l + 64*j;
        if (d < DP) {
            float acc = 0.f;
            for (int c = 0; c < CIN; c += 4) {
                float4 cf4 = *(const float4*)&s_cf[g][c];
                acc = fmaf(cf4.x, Mt[(size_t)(c+0)*DP + d], acc);
                acc = fmaf(cf4.y, Mt[(size_t)(c+1)*DP + d], acc);
                acc = fmaf(cf4.z, Mt[(size_t)(c+2)*DP + d], acc);
                acc = fmaf(cf4.w, Mt[(size_t)(c+3)*DP + d], acc);
            }
            s_u[g][d] = acc;
        }
    }
    __syncthreads();

    // ---- scores[g][kk] = (u[g] . fea[g][kk]) / 16  (two dots per wave) ----
#pragma unroll
    for (int it = 0; it < 16; ++it) {
        int kk = it*2 + h32;
        float acc = 0.f;
        for (int c = l31; c < DP/4; c += 32) {
            float4 f4 = *(const float4*)&s_fea[g][kk][c*4];
            float4 u4 = *(const float4*)&s_u[g][c*4];
            acc = fmaf(f4.x,u4.x,acc); acc = fmaf(f4.y,u4.y,acc);
            acc = fmaf(f4.z,u4.z,acc); acc = fmaf(f4.w,u4.w,acc);
        }
#pragma unroll
        for (int off = 16; off; off >>= 1) acc += __shfl_xor(acc, off);
        if (l31 == 0) s_sc[g][kk] = acc * 0.0625f;
    }
    __syncthreads();

    // ---- softmax over 32 (lanes 0..31 of wave g) ----
    if (l < KNN) {
        float sc = s_sc[g][l];
        float m = sc;
#pragma unroll
        for (int off = 16; off; off >>= 1) m = fmaxf(m, __shfl_xor(m, off));
        float e = expf(sc - m);
        float ssum = e;
#pragma unroll
        for (int off = 16; off; off >>= 1) ssum += __shfl_xor(ssum, off);
        s_sc[g][l] = e / ssum;
    }
    __syncthreads();

    // ---- wfea[g][d] = sum_k attn[g][k] * fea[g][k][d]  (f4 chunks) ----
    if (l < DP/4) {
        const int d0 = l*4;
        float w0=0.f, w1=0.f, w2=0.f, w3=0.f;
#pragma unroll
        for (int k4 = 0; k4 < KNN; k4 += 4) {
            float4 a  = *(const float4*)&s_sc[g][k4];
            float4 f0 = *(const float4*)&s_fea[g][k4+0][d0];
            float4 f1 = *(const float4*)&s_fea[g][k4+1][d0];
            float4 f2 = *(const float4*)&s_fea[g][k4+2][d0];
            float4 f3 = *(const float4*)&s_fea[g][k4+3][d0];
            w0=fmaf(a.x,f0.x,w0); w1=fmaf(a.x,f0.y,w1); w2=fmaf(a.x,f0.z,w2); w3=fmaf(a.x,f0.w,w3);
            w0=fmaf(a.y,f1.x,w0); w1=fmaf(a.y,f1.y,w1); w2=fmaf(a.y,f1.z,w2); w3=fmaf(a.y,f1.w,w3);
            w0=fmaf(a.z,f2.x,w0); w1=fmaf(a.z,f2.y,w1); w2=fmaf(a.z,f2.z,w2); w3=fmaf(a.z,f2.w,w3);
            w0=fmaf(a.w,f3.x,w0); w1=fmaf(a.w,f3.y,w1); w2=fmaf(a.w,f3.z,w2); w3=fmaf(a.w,f3.w,w3);
        }
        s_wf[g][d0+0]=w0; s_wf[g][d0+1]=w1; s_wf[g][d0+2]=w2; s_wf[g][d0+3]=w3;
    }
    __syncthreads();

    // ---- o[g][h=t] = sum_d wf[g][d] * Wvp[d][h]  (cross-wave, coalesced) ----
    float o0=0.f, o1=0.f, o2=0.f, o3=0.f;
    for (int d4 = 0; d4 < DP/4; ++d4) {
        float4 wf0 = *(const float4*)&s_wf[0][d4*4];
        float4 wf1 = *(const float4*)&s_wf[1][d4*4];
        float4 wf2 = *(const float4*)&s_wf[2][d4*4];
        float4 wf3 = *(const float4*)&s_wf[3][d4*4];
        float v0 = Wvpt[(size_t)(d4*4+0)*CO + t];
        float v1 = Wvpt[(size_t)(d4*4+1)*CO + t];
        float v2 = Wvpt[(size_t)(d4*4+2)*CO + t];
        float v3 = Wvpt[(size_t)(d4*4+3)*CO + t];
        o0=fmaf(wf0.x,v0,o0); o0=fmaf(wf0.y,v1,o0); o0=fmaf(wf0.z,v2,o0); o0=fmaf(wf0.w,v3,o0);
        o1=fmaf(wf1.x,v0,o1); o1=fmaf(wf1.y,v1,o1); o1=fmaf(wf1.z,v2,o1); o1=fmaf(wf1.w,v3,o1);
        o2=fmaf(wf2.x,v0,o2); o2=fmaf(wf2.y,v1,o2); o2=fmaf(wf2.z,v2,o2); o2=fmaf(wf2.w,v3,o2);
        o3=fmaf(wf3.x,v0,o3); o3=fmaf(wf3.y,v1,o3); o3=fmaf(wf3.z,v2,o3); o3=fmaf(wf3.w,v3,o3);
    }
    outp[(size_t)(bs0+0)*CO + t] = o0;
    outp[(size_t)(bs0+1)*CO + t] = o1;
    outp[(size_t)(bs0+2)*CO + t] = o2;
    outp[(size_t)(bs0+3)*CO + t] = o3;
    __syncthreads();
}

__global__ __launch_bounds__(256) void attn_kernel(
    const float* __restrict__ xyz, const float* __restrict__ mad,
    const float* __restrict__ adj, const float* __restrict__ pt,
    const float* __restrict__ mad_fea, const float* __restrict__ adj_fea,
    const float* __restrict__ pt_fea,  const float* __restrict__ cst_fea,
    const float* __restrict__ M, const float* __restrict__ Wvp,
    const int* __restrict__ fps_idx, const int* __restrict__ nbr_idx,
    float* __restrict__ out)
{
    __shared__ float s_cf[4][CIN];
    __shared__ float s_u[4][DP];
    __shared__ float s_fea[4][KNN][DP];
    __shared__ float s_sc[4][KNN];
    __shared__ float s_wf[4][DP];
    __shared__ int   s_nbr4[4][KNN];
    __shared__ int   s_ci4[4];

    const int bs0 = blockIdx.x * 4;
    const int b   = bs0 >> 10;
    const int t   = threadIdx.x;
    const int g   = t >> 6, l = t & 63;

    if (t < 4) s_ci4[t] = fps_idx[bs0 + t];
    if (t < 128) s_nbr4[t>>5][t&31] = nbr_idx[(bs0 + (t>>5))*KNN + (t&31)];
    __syncthreads();
    const int ci = s_ci4[g];

    // small per-center outputs (wave-private)
    if (l < 3)             out[OFF_CXYZ + (bs0+g)*3 + l]      = xyz[(size_t)(b*NPTS+ci)*3 + l];
    if (l >= 4 && l < 7)   out[OFF_CMAD + (bs0+g)*3 + (l-4)]  = mad[(size_t)(b*NPTS+ci)*3 + (l-4)];
    if (l >= 8 && l < 10)  out[OFF_CADJ + (bs0+g)*2 + (l-8)]  = adj[(size_t)(b*NPTS+ci)*2 + (l-8)];
    if (l >= 12 && l < 16) out[OFF_CPT  + (bs0+g)*4 + (l-12)] = pt[(size_t)(b*NPTS+ci)*4 + (l-12)];

    attn_t<0>(b, bs0, ci, mad_fea, mad, M + 0*CIN*DP, Wvp + 0*DP*CO, out + OFF_OMAD,
              s_cf, s_u, s_fea, s_sc, s_wf, s_nbr4);
    attn_t<1>(b, bs0, ci, adj_fea, adj, M + 1*CIN*DP, Wvp + 1*DP*CO, out + OFF_OADJ,
              s_cf, s_u, s_fea, s_sc, s_wf, s_nbr4);
    attn_t<2>(b, bs0, ci, pt_fea,  pt,  M + 2*CIN*DP, Wvp + 2*DP*CO, out + OFF_OPT,
              s_cf, s_u, s_fea, s_sc, s_wf, s_nbr4);
    attn_t<3>(b, bs0, ci, cst_fea, xyz, M + 3*CIN*DP, Wvp + 3*DP*CO, out + OFF_OCST,
              s_cf, s_u, s_fea, s_sc, s_wf, s_nbr4);
}

extern "C" void kernel_launch(void* const* d_in, const int* in_sizes, int n_in,
                              void* d_out, int out_size, void* d_ws, size_t ws_size,
                              hipStream_t stream)
{
    const float* xyz     = (const float*)d_in[0];
    const float* mad     = (const float*)d_in[1];
    const float* adj     = (const float*)d_in[2];
    const float* pt      = (const float*)d_in[3];
    const float* mad_fea = (const float*)d_in[4];
    const float* adj_fea = (const float*)d_in[5];
    const float* pt_fea  = (const float*)d_in[6];
    const float* cst_fea = (const float*)d_in[7];
    const float* wq_mad  = (const float*)d_in[8];
    const float* wk_mad  = (const float*)d_in[9];
    const float* wv_mad  = (const float*)d_in[10];
    const float* wq_adj  = (const float*)d_in[11];
    const float* wk_adj  = (const float*)d_in[12];
    const float* wv_adj  = (const float*)d_in[13];
    const float* wq_pt   = (const float*)d_in[14];
    const float* wk_pt   = (const float*)d_in[15];
    const float* wv_pt   = (const float*)d_in[16];
    const float* wq_cst  = (const float*)d_in[17];
    const float* wk_cst  = (const float*)d_in[18];
    const float* wv_cst  = (const float*)d_in[19];
    float* out = (float*)d_out;

    int*   fps_idx = (int*)d_ws;                      // 4096 ints
    int*   nbr_idx = fps_idx + BATCH*NC;              // 131072 ints
    float* M       = (float*)(nbr_idx + BATCH*NC*KNN);// 4*128*136 floats
    float* Wvp     = M + 4*CIN*DP;                    // 4*136*256 floats

    fps_prep_kernel<<<BATCH + 4*DP, 256, 0, stream>>>(xyz, fps_idx,
        wq_mad, wk_mad, wv_mad, wq_adj, wk_adj, wv_adj,
        wq_pt, wk_pt, wv_pt, wq_cst, wk_cst, wv_cst, M, Wvp);
    knn_kernel<<<BATCH*NC, 256, 0, stream>>>(xyz, fps_idx, nbr_idx);
    attn_kernel<<<BATCH*NC/4, 256, 0, stream>>>(xyz, mad, adj, pt,
        mad_fea, adj_fea, pt_fea, cst_fea, M, Wvp, fps_idx, nbr_idx, out);
}